// Round 6
// baseline (207.094 us; speedup 1.0000x reference)
//
#include <hip/hip_runtime.h>
#include <math.h>

// CascadeGCN: 2-layer GCN, N=100000, E=2.5M, 5 -> 32 -> 1.
// R6: zero per-edge LDS atomics. Wave-level same-key grouping via __ballot
// masks: one leader lane per distinct key does a plain LDS RMW into
// wave-private histograms/cursors (distinct keys => distinct addresses within
// the wave; wave-private arrays => no cross-wave races).
// Pipeline: init -> part -> sortb -> agg1 -> agg2.

#define NB_SHIFT  8          // 256 nodes per bucket
#define BNODES    256
#define NBK       512        // part key space (nb = 391, padded)
#define CAP       8192       // bucket capacity (mean 6400)
#define CAP_SHIFT 13
#define CHUNK     8192
#define PBLK      256        // 4 waves
#define NW        4

// same-key mask among valid lanes of this wave (BITS-bit keys)
template <int BITS>
__device__ __forceinline__ unsigned long long grp_mask(int k, bool valid) {
    unsigned long long m = __ballot(valid ? 1 : 0);
#pragma unroll
    for (int i = 0; i < BITS; ++i) {
        unsigned long long b = __ballot((k >> i) & 1);
        m &= ((k >> i) & 1) ? b : ~b;
    }
    return m;
}

// ---- init fixed-capacity bucket cursors ----
__global__ void k_init(int* __restrict__ bcur) {
    int b = threadIdx.x;
    if (b < NBK) bcur[b] = b << CAP_SHIFT;
}

// ---- bucket partition, atomic-free grouping; packed 4 B records ----
__global__ __launch_bounds__(PBLK) void k_part(const int* __restrict__ src,
                                               const int* __restrict__ dst, int E,
                                               int* __restrict__ bcur,
                                               int* __restrict__ pairs) {
    __shared__ int sp[CHUNK];                 // 32 KB records
    __shared__ unsigned short sb[CHUNK];      // 16 KB bucket ids
    __shared__ int hw[NW * NBK];              // 8 KB wave-private hist -> cur
    __shared__ int ofs[NBK];                  // chunk-local key starts
    __shared__ int gbase[NBK];                // reserved global bases
    __shared__ int tsum[PBLK];
    int tid = threadIdx.x, lane = tid & 63, w = tid >> 6;
    int base = blockIdx.x * CHUNK;
    int m = min(CHUNK, E - base);
    int iters = (m + PBLK - 1) / PBLK;

    for (int i = tid; i < NW * NBK; i += PBLK) hw[i] = 0;
    __syncthreads();
    int* hwr = hw + w * NBK;

    // pass 1: grouped histogram (leader-only plain RMW)
    for (int it = 0; it < iters; ++it) {
        int i = it * PBLK + tid;
        bool valid = i < m;
        int k = valid ? (dst[base + i] >> NB_SHIFT) : 0;
        unsigned long long g = grp_mask<9>(k, valid);
        if (valid && lane == (__ffsll((long long)g) - 1))
            hwr[k] += __popcll(g);
    }
    __syncthreads();

    // scan over 512 keys (thread owns 2) + per-wave cur bases in place
    int b0 = tid * 2;
    int h0[NW], h1[NW], s0 = 0, s1 = 0;
#pragma unroll
    for (int j = 0; j < NW; ++j) {
        h0[j] = hw[j * NBK + b0];     s0 += h0[j];
        h1[j] = hw[j * NBK + b0 + 1]; s1 += h1[j];
    }
    int tot = s0 + s1;
    tsum[tid] = tot;
    __syncthreads();
    for (int off = 1; off < PBLK; off <<= 1) {
        int u = (tid >= off) ? tsum[tid - off] : 0;
        __syncthreads();
        tsum[tid] += u;
        __syncthreads();
    }
    int pre = tsum[tid] - tot;
    ofs[b0] = pre;  ofs[b0 + 1] = pre + s0;
    int r0 = pre, r1 = pre + s0;
#pragma unroll
    for (int j = 0; j < NW; ++j) {
        hw[j * NBK + b0] = r0;     r0 += h0[j];
        hw[j * NBK + b0 + 1] = r1; r1 += h1[j];
    }
    gbase[b0]     = s0 ? atomicAdd(&bcur[b0], s0) : 0;
    gbase[b0 + 1] = s1 ? atomicAdd(&bcur[b0 + 1], s1) : 0;
    __syncthreads();

    // pass 2: grouped scatter into LDS (bucket-ordered)
    for (int it = 0; it < iters; ++it) {
        int i = it * PBLK + tid;
        bool valid = i < m;
        int s = 0, d = 0;
        if (valid) { s = src[base + i]; d = dst[base + i]; }
        int k = valid ? (d >> NB_SHIFT) : 0;
        unsigned long long g = grp_mask<9>(k, valid);
        int rank = __popcll(g & ((1ull << lane) - 1ull));
        int pb = valid ? hwr[k] : 0;          // read before leader update
        if (valid) {
            int p = pb + rank;
            sp[p] = ((d & (BNODES - 1)) << 24) | s;
            sb[p] = (unsigned short)k;
        }
        if (valid && lane == (__ffsll((long long)g) - 1))
            hwr[k] = pb + __popcll(g);
    }
    __syncthreads();

    // coalesced writeout
    for (int i = tid; i < m; i += PBLK) {
        int b = sb[i];
        pairs[gbase[b] + (i - ofs[b])] = sp[i];
    }
}

// ---- per-bucket counting sort by node, atomic-free; dinv/nofs/deg/xs prep ----
__global__ __launch_bounds__(BNODES) void k_sortb(int* __restrict__ pairs,
                                                  const int* __restrict__ bcur,
                                                  const float* __restrict__ x,
                                                  float* __restrict__ dinv,
                                                  float* __restrict__ xs,
                                                  int* __restrict__ nofs,
                                                  int* __restrict__ deg, int n) {
    __shared__ int stage2[CAP];               // 32 KB
    __shared__ int hw[NW * BNODES];           // 4 KB wave-private hist -> cur
    __shared__ int scn[BNODES];
    int tid = threadIdx.x, lane = tid & 63, w = tid >> 6;
    int b = blockIdx.x;
    int base = b << CAP_SHIFT;
    int len = min(bcur[b] - base, CAP);
    int iters = (len + BNODES - 1) / BNODES;

    for (int i = tid; i < NW * BNODES; i += BNODES) hw[i] = 0;
    __syncthreads();
    int* hwr = hw + w * BNODES;

    // pass 1: grouped histogram of node-low-byte
    for (int it = 0; it < iters; ++it) {
        int i = it * BNODES + tid;
        bool valid = i < len;
        int k = valid ? (int)(((unsigned)pairs[base + i]) >> 24) : 0;
        unsigned long long g = grp_mask<8>(k, valid);
        if (valid && lane == (__ffsll((long long)g) - 1))
            hwr[k] += __popcll(g);
    }
    __syncthreads();

    // scan over 256 node keys (thread owns 1) + per-wave cur bases
    int hv[NW], tot = 0;
#pragma unroll
    for (int j = 0; j < NW; ++j) { hv[j] = hw[j * BNODES + tid]; tot += hv[j]; }
    scn[tid] = tot;
    __syncthreads();
    for (int off = 1; off < BNODES; off <<= 1) {
        int u = (tid >= off) ? scn[tid - off] : 0;
        __syncthreads();
        scn[tid] += u;
        __syncthreads();
    }
    int pos = scn[tid] - tot;                 // exclusive
    int r = pos;
#pragma unroll
    for (int j = 0; j < NW; ++j) { hw[j * BNODES + tid] = r; r += hv[j]; }
    int node = (b << NB_SHIFT) + tid;
    if (node < n) {
        nofs[node] = base + pos;
        deg[node] = tot;
        float di = rsqrtf((float)tot + 1.0f);
        dinv[node] = di;
        const float* xr = x + (size_t)node * 5;
        float* xo = xs + ((size_t)node << 3);
#pragma unroll
        for (int k = 0; k < 5; ++k) xo[k] = xr[k] * di;
    }
    __syncthreads();

    // pass 2: grouped scatter (src-only) into stage2
    for (int it = 0; it < iters; ++it) {
        int i = it * BNODES + tid;
        bool valid = i < len;
        int v = valid ? pairs[base + i] : 0;
        int k = (int)(((unsigned)v) >> 24);
        unsigned long long g = grp_mask<8>(k, valid);
        int rank = __popcll(g & ((1ull << lane) - 1ull));
        int pb = valid ? hwr[k] : 0;
        if (valid) stage2[pb + rank] = v & 0x00FFFFFF;
        if (valid && lane == (__ffsll((long long)g) - 1))
            hwr[k] = pb + __popcll(g);
    }
    __syncthreads();
    for (int i = tid; i < len; i += BNODES) pairs[base + i] = stage2[i];
}

// ---- layer-1: register accumulation over per-node run + fused W1/relu/W2 ----
__global__ __launch_bounds__(256) void k_agg1(const int* __restrict__ pairs,
                                              const int* __restrict__ nofs,
                                              const int* __restrict__ deg,
                                              const float* __restrict__ xs,
                                              const float* __restrict__ dinv,
                                              const float* __restrict__ W1,
                                              const float* __restrict__ b1,
                                              const float* __restrict__ W2,
                                              float* __restrict__ h2s, int n) {
    __shared__ float w1[160], bb1[32], w2[32];
    int tid = threadIdx.x;
    if (tid < 160) w1[tid] = W1[tid];
    else if (tid < 192) bb1[tid - 160] = b1[tid - 160];
    else if (tid < 224) w2[tid - 192] = W2[tid - 192];
    __syncthreads();
    int node = blockIdx.x * 128 + (tid >> 1);
    int half = tid & 1;
    if (node >= n) return;
    int beg = nofs[node], dg = deg[node];
    float a0 = 0.f, a1 = 0.f, a2 = 0.f, a3 = 0.f, a4 = 0.f;
    if (!half) {                                   // self-loop term
        const float* xo = xs + ((size_t)node << 3);
        a0 = xo[0]; a1 = xo[1]; a2 = xo[2]; a3 = xo[3]; a4 = xo[4];
    }
    for (int e = beg + half; e < beg + dg; e += 2) {
        int s = pairs[e];
        const float* xr = xs + ((size_t)s << 3);
        float4 q = *(const float4*)xr;
        float q4 = xr[4];
        a0 += q.x; a1 += q.y; a2 += q.z; a3 += q.w; a4 += q4;
    }
    a0 += __shfl_xor(a0, 1); a1 += __shfl_xor(a1, 1); a2 += __shfl_xor(a2, 1);
    a3 += __shfl_xor(a3, 1); a4 += __shfl_xor(a4, 1);
    if (half) return;
    float di = dinv[node];
    a0 *= di; a1 *= di; a2 *= di; a3 *= di; a4 *= di;
    float sum = 0.f;
#pragma unroll
    for (int c = 0; c < 32; ++c) {
        float z = bb1[c] + a0 * w1[c] + a1 * w1[32 + c] + a2 * w1[64 + c]
                         + a3 * w1[96 + c] + a4 * w1[128 + c];
        sum += fmaxf(z, 0.f) * w2[c];
    }
    h2s[node] = sum * di;                          // pre-scale by source dinv
}

// ---- layer-2: register accumulation + sigmoid ----
__global__ __launch_bounds__(256) void k_agg2(const int* __restrict__ pairs,
                                              const int* __restrict__ nofs,
                                              const int* __restrict__ deg,
                                              const float* __restrict__ h2s,
                                              const float* __restrict__ dinv,
                                              const float* __restrict__ b2,
                                              float* __restrict__ out, int n) {
    int tid = threadIdx.x;
    int node = blockIdx.x * 128 + (tid >> 1);
    int half = tid & 1;
    if (node >= n) return;
    int beg = nofs[node], dg = deg[node];
    float a = 0.f;
    for (int e = beg + half; e < beg + dg; e += 2) a += h2s[pairs[e]];
    a += __shfl_xor(a, 1);
    if (half) return;
    float v = dinv[node] * (a + h2s[node]) + b2[0];
    out[node] = 1.0f / (1.0f + __expf(-v));
}

extern "C" void kernel_launch(void* const* d_in, const int* in_sizes, int n_in,
                              void* d_out, int out_size, void* d_ws, size_t ws_size,
                              hipStream_t stream) {
    const float* x  = (const float*)d_in[0];
    const int*   ei = (const int*)d_in[1];
    const float* W1 = (const float*)d_in[2];
    const float* b1 = (const float*)d_in[3];
    const float* W2 = (const float*)d_in[4];
    const float* b2 = (const float*)d_in[5];
    float* out = (float*)d_out;

    const int n = in_sizes[0] / 5;       // 100000
    const int E = in_sizes[1] / 2;       // 2500000
    const int* src = ei;
    const int* dst = ei + E;
    const int nb = (n + BNODES - 1) >> NB_SHIFT;   // 391

    // ws (4B units, 16B-aligned):
    // [pairs (nb+1)<<13][nofs n][deg n][dinv n][h2s n][xs 8n][bcur NBK]
    int* wsi = (int*)d_ws;
    int*   pairs = wsi;
    int*   nofs  = wsi + ((size_t)(nb + 1) << CAP_SHIFT);
    int*   deg   = nofs + n;
    float* dinv  = (float*)(deg + n);
    float* h2s   = dinv + n;
    float* xs    = h2s + n;
    int*   bcur  = (int*)(xs + (size_t)8 * n);

    const int nchunk = (E + CHUNK - 1) / CHUNK;    // 306
    const int nagg   = (n + 127) / 128;            // 782

    k_init<<<1, NBK, 0, stream>>>(bcur);
    k_part<<<nchunk, PBLK, 0, stream>>>(src, dst, E, bcur, pairs);
    k_sortb<<<nb, BNODES, 0, stream>>>(pairs, bcur, x, dinv, xs, nofs, deg, n);
    k_agg1<<<nagg, 256, 0, stream>>>(pairs, nofs, deg, xs, dinv, W1, b1, W2, h2s, n);
    k_agg2<<<nagg, 256, 0, stream>>>(pairs, nofs, deg, h2s, dinv, b2, out, n);
}

// Round 7
// 178.917 us; speedup vs baseline: 1.1575x; 1.1575x over previous
//
#include <hip/hip_runtime.h>
#include <math.h>

// CascadeGCN: 2-layer GCN, N=100000, E=2.5M, 5 -> 32 -> 1.
// R7: R5 structure (LDS-atomic two-level counting sort) with 128-node
// level-2 buckets: sortb grid 391->782 blocks, staging LDS halved -> 4
// blocks/CU. Ballot grouping reverted (R6 lesson: random keys => ~unique
// per wave => ballots cost more than low-contention LDS atomics).
// Pipeline: init -> part -> sortb -> agg1 -> agg2.

#define NB_SHIFT  7          // 128 nodes per bucket
#define BNODES    128
#define NBK       1024       // level-1 key space (nb = 782, padded)
#define CAP       4096       // bucket capacity (mean 3200, +15.8 sigma)
#define CAP_SHIFT 12
#define CHUNK     8192
#define PBLK      256

// ---- init fixed-capacity bucket cursors ----
__global__ void k_init(int* __restrict__ bcur) {
    int b = threadIdx.x;
    if (b < NBK) bcur[b] = b << CAP_SHIFT;
}

// ---- LDS-staged bucket partition; packed 4 B records (dlow<<24 | src) ----
__global__ __launch_bounds__(PBLK) void k_part(const int* __restrict__ src,
                                               const int* __restrict__ dst, int E,
                                               int* __restrict__ bcur,
                                               int* __restrict__ pairs) {
    __shared__ int sp[CHUNK];                 // 32 KB records
    __shared__ unsigned short sb[CHUNK];      // 16 KB bucket ids
    __shared__ int cnt[NBK], cur[NBK], gbase[NBK];   // 12 KB
    __shared__ int tsum[PBLK];                // 1 KB
    int tid = threadIdx.x;
    int base = blockIdx.x * CHUNK;
    int m = min(CHUNK, E - base);

    for (int b = tid; b < NBK; b += PBLK) cnt[b] = 0;
    __syncthreads();
    // pass 1: histogram
    for (int i = tid; i < m; i += PBLK)
        atomicAdd(&cnt[dst[base + i] >> NB_SHIFT], 1);
    __syncthreads();
    // exclusive scan over 1024 keys: each thread owns 4 consecutive
    int k0 = tid * 4;
    int c0 = cnt[k0], c1 = cnt[k0 + 1], c2 = cnt[k0 + 2], c3 = cnt[k0 + 3];
    int tot = c0 + c1 + c2 + c3;
    tsum[tid] = tot;
    __syncthreads();
    for (int off = 1; off < PBLK; off <<= 1) {
        int u = (tid >= off) ? tsum[tid - off] : 0;
        __syncthreads();
        tsum[tid] += u;
        __syncthreads();
    }
    int r = tsum[tid] - tot;                  // exclusive prefix
    cur[k0] = r;                 gbase[k0]     = c0 ? atomicAdd(&bcur[k0], c0) : 0;
    cur[k0 + 1] = r + c0;        gbase[k0 + 1] = c1 ? atomicAdd(&bcur[k0 + 1], c1) : 0;
    cur[k0 + 2] = r + c0 + c1;   gbase[k0 + 2] = c2 ? atomicAdd(&bcur[k0 + 2], c2) : 0;
    cur[k0 + 3] = r + c0 + c1 + c2;
    gbase[k0 + 3] = c3 ? atomicAdd(&bcur[k0 + 3], c3) : 0;
    __syncthreads();
    // pass 2: bucket-ordered scatter into LDS
    for (int i = tid; i < m; i += PBLK) {
        int s = src[base + i], d = dst[base + i];
        int k = d >> NB_SHIFT;
        int p = atomicAdd(&cur[k], 1);
        sp[p] = ((d & (BNODES - 1)) << 24) | s;
        sb[p] = (unsigned short)k;
    }
    __syncthreads();
    // coalesced-run writeout (start of run b = cur[b] - cnt[b])
    for (int i = tid; i < m; i += PBLK) {
        int b = sb[i];
        int start = cur[b] - cnt[b];
        pairs[gbase[b] + (i - start)] = sp[i];
    }
}

// ---- per-bucket counting sort by node (LDS) + dinv/nofs/deg/xs prep ----
__global__ __launch_bounds__(256) void k_sortb(int* __restrict__ pairs,
                                               const int* __restrict__ bcur,
                                               const float* __restrict__ x,
                                               float* __restrict__ dinv,
                                               float* __restrict__ xs,
                                               int* __restrict__ nofs,
                                               int* __restrict__ deg, int n) {
    __shared__ int stage[CAP];                // 16 KB
    __shared__ int stage2[CAP];               // 16 KB
    __shared__ int cnt[BNODES], cur[BNODES], scn[BNODES];   // 1.5 KB
    int tid = threadIdx.x;
    int b = blockIdx.x;
    int base = b << CAP_SHIFT;
    int len = min(bcur[b] - base, CAP);

    for (int i = tid; i < len; i += 256) stage[i] = pairs[base + i];
    if (tid < BNODES) cnt[tid] = 0;
    __syncthreads();
    for (int i = tid; i < len; i += 256)
        atomicAdd(&cnt[((unsigned)stage[i]) >> 24], 1);
    __syncthreads();
    int v = (tid < BNODES) ? cnt[tid] : 0;
    if (tid < BNODES) scn[tid] = v;
    __syncthreads();
    for (int off = 1; off < BNODES; off <<= 1) {   // Hillis-Steele inclusive
        int u = (tid < BNODES && tid >= off) ? scn[tid - off] : 0;
        __syncthreads();
        if (tid < BNODES) scn[tid] += u;
        __syncthreads();
    }
    if (tid < BNODES) {
        int pos = scn[tid] - v;                    // exclusive
        cur[tid] = pos;
        int node = (b << NB_SHIFT) + tid;
        if (node < n) {
            nofs[node] = base + pos;
            deg[node] = v;
            float di = rsqrtf((float)v + 1.0f);
            dinv[node] = di;
            const float* xr = x + (size_t)node * 5;
            float* xo = xs + ((size_t)node << 3);  // padded row: 8 floats
#pragma unroll
            for (int k = 0; k < 5; ++k) xo[k] = xr[k] * di;
        }
    }
    __syncthreads();
    for (int i = tid; i < len; i += 256) {
        int vv = stage[i];
        int p = atomicAdd(&cur[((unsigned)vv) >> 24], 1);
        stage2[p] = vv & 0x00FFFFFF;               // src only
    }
    __syncthreads();
    for (int i = tid; i < len; i += 256) pairs[base + i] = stage2[i];
}

// ---- layer-1: register accumulation over per-node run + fused W1/relu/W2 ----
__global__ __launch_bounds__(256) void k_agg1(const int* __restrict__ pairs,
                                              const int* __restrict__ nofs,
                                              const int* __restrict__ deg,
                                              const float* __restrict__ xs,
                                              const float* __restrict__ dinv,
                                              const float* __restrict__ W1,
                                              const float* __restrict__ b1,
                                              const float* __restrict__ W2,
                                              float* __restrict__ h2s, int n) {
    __shared__ float w1[160], bb1[32], w2[32];
    int tid = threadIdx.x;
    if (tid < 160) w1[tid] = W1[tid];
    else if (tid < 192) bb1[tid - 160] = b1[tid - 160];
    else if (tid < 224) w2[tid - 192] = W2[tid - 192];
    __syncthreads();
    int node = blockIdx.x * 128 + (tid >> 1);
    int half = tid & 1;
    if (node >= n) return;
    int beg = nofs[node], dg = deg[node];
    float a0 = 0.f, a1 = 0.f, a2 = 0.f, a3 = 0.f, a4 = 0.f;
    if (!half) {                                   // self-loop term
        const float* xo = xs + ((size_t)node << 3);
        a0 = xo[0]; a1 = xo[1]; a2 = xo[2]; a3 = xo[3]; a4 = xo[4];
    }
    for (int e = beg + half; e < beg + dg; e += 2) {
        int s = pairs[e];
        const float* xr = xs + ((size_t)s << 3);
        float4 q = *(const float4*)xr;
        float q4 = xr[4];
        a0 += q.x; a1 += q.y; a2 += q.z; a3 += q.w; a4 += q4;
    }
    a0 += __shfl_xor(a0, 1); a1 += __shfl_xor(a1, 1); a2 += __shfl_xor(a2, 1);
    a3 += __shfl_xor(a3, 1); a4 += __shfl_xor(a4, 1);
    if (half) return;
    float di = dinv[node];
    a0 *= di; a1 *= di; a2 *= di; a3 *= di; a4 *= di;
    float sum = 0.f;
#pragma unroll
    for (int c = 0; c < 32; ++c) {
        float z = bb1[c] + a0 * w1[c] + a1 * w1[32 + c] + a2 * w1[64 + c]
                         + a3 * w1[96 + c] + a4 * w1[128 + c];
        sum += fmaxf(z, 0.f) * w2[c];
    }
    h2s[node] = sum * di;                          // pre-scale by source dinv
}

// ---- layer-2: register accumulation + sigmoid ----
__global__ __launch_bounds__(256) void k_agg2(const int* __restrict__ pairs,
                                              const int* __restrict__ nofs,
                                              const int* __restrict__ deg,
                                              const float* __restrict__ h2s,
                                              const float* __restrict__ dinv,
                                              const float* __restrict__ b2,
                                              float* __restrict__ out, int n) {
    int tid = threadIdx.x;
    int node = blockIdx.x * 128 + (tid >> 1);
    int half = tid & 1;
    if (node >= n) return;
    int beg = nofs[node], dg = deg[node];
    float a = 0.f;
    for (int e = beg + half; e < beg + dg; e += 2) a += h2s[pairs[e]];
    a += __shfl_xor(a, 1);
    if (half) return;
    float v = dinv[node] * (a + h2s[node]) + b2[0];
    out[node] = 1.0f / (1.0f + __expf(-v));
}

extern "C" void kernel_launch(void* const* d_in, const int* in_sizes, int n_in,
                              void* d_out, int out_size, void* d_ws, size_t ws_size,
                              hipStream_t stream) {
    const float* x  = (const float*)d_in[0];
    const int*   ei = (const int*)d_in[1];
    const float* W1 = (const float*)d_in[2];
    const float* b1 = (const float*)d_in[3];
    const float* W2 = (const float*)d_in[4];
    const float* b2 = (const float*)d_in[5];
    float* out = (float*)d_out;

    const int n = in_sizes[0] / 5;       // 100000
    const int E = in_sizes[1] / 2;       // 2500000
    const int* src = ei;
    const int* dst = ei + E;
    const int nb = (n + BNODES - 1) >> NB_SHIFT;   // 782

    // ws (4B units, 16B-aligned):
    // [pairs NBK<<12 = 4.19M ints][nofs n][deg n][dinv n][h2s n][xs 8n][bcur NBK]
    int* wsi = (int*)d_ws;
    int*   pairs = wsi;
    int*   nofs  = wsi + ((size_t)NBK << CAP_SHIFT);
    int*   deg   = nofs + n;
    float* dinv  = (float*)(deg + n);
    float* h2s   = dinv + n;
    float* xs    = h2s + n;
    int*   bcur  = (int*)(xs + (size_t)8 * n);

    const int nchunk = (E + CHUNK - 1) / CHUNK;    // 306
    const int nagg   = (n + 127) / 128;            // 782

    k_init<<<1, NBK, 0, stream>>>(bcur);
    k_part<<<nchunk, PBLK, 0, stream>>>(src, dst, E, bcur, pairs);
    k_sortb<<<nb, 256, 0, stream>>>(pairs, bcur, x, dinv, xs, nofs, deg, n);
    k_agg1<<<nagg, 256, 0, stream>>>(pairs, nofs, deg, xs, dinv, W1, b1, W2, h2s, n);
    k_agg2<<<nagg, 256, 0, stream>>>(pairs, nofs, deg, h2s, dinv, b2, out, n);
}